// Round 1
// baseline (606.473 us; speedup 1.0000x reference)
//
#include <hip/hip_runtime.h>
#include <math.h>

#define B_   8
#define N_   16384
#define M_   64
#define C_   192
#define RC_  16

typedef float f32x4 __attribute__((ext_vector_type(4)));

__device__ __forceinline__ void nt_store4(float* p, float a, float b, float c, float d)
{
    f32x4 v; v[0] = a; v[1] = b; v[2] = c; v[3] = d;
    __builtin_nontemporal_store(v, (f32x4*)p);
}

// ---------------------------------------------------------------------------
// K1: v[b,m,c] = dict[b,m,:] @ wv_w[:,c] + wv_b[c]
// ---------------------------------------------------------------------------
__global__ __launch_bounds__(256) void k_v_kernel(
    const float* __restrict__ dict, const float* __restrict__ wv_w,
    const float* __restrict__ wv_b, float* __restrict__ ws_v)
{
    const int idx = blockIdx.x * 256 + threadIdx.x;   // (b*64+m)*192 + c
    const int c   = idx % C_;
    const int row = idx / C_;
    const float* dr = dict + row * C_;
    float acc = wv_b[c];
    #pragma unroll 4
    for (int d = 0; d < C_; ++d)
        acc = fmaf(dr[d], wv_w[d * C_ + c], acc);
    ws_v[idx] = acc;
}

// ---------------------------------------------------------------------------
// K2: k[b,m,:] = l2norm(layernorm(dict[b,m,:] @ wk_w + wk_b))
//     one block per b; thread = (m, j4); j4 owns 4 of 16 components.
// ---------------------------------------------------------------------------
__global__ __launch_bounds__(256) void k_k_kernel(
    const float* __restrict__ dict, const float* __restrict__ wk_w,
    const float* __restrict__ wk_b, const float* __restrict__ kn_g,
    const float* __restrict__ kn_b, float* __restrict__ ws_k)
{
    const int b  = blockIdx.x;
    const int m  = threadIdx.x >> 2;
    const int j4 = threadIdx.x & 3;
    const int c0 = j4 * 4;
    const float* dr = dict + (b * M_ + m) * C_;

    float a0 = wk_b[c0+0], a1 = wk_b[c0+1], a2 = wk_b[c0+2], a3 = wk_b[c0+3];
    #pragma unroll 4
    for (int d4 = 0; d4 < C_/4; ++d4) {
        const float4 xv = ((const float4*)dr)[d4];
        const float4 w0 = *(const float4*)&wk_w[(d4*4+0)*RC_ + c0];
        const float4 w1 = *(const float4*)&wk_w[(d4*4+1)*RC_ + c0];
        const float4 w2 = *(const float4*)&wk_w[(d4*4+2)*RC_ + c0];
        const float4 w3 = *(const float4*)&wk_w[(d4*4+3)*RC_ + c0];
        a0 = fmaf(xv.x, w0.x, a0); a1 = fmaf(xv.x, w0.y, a1); a2 = fmaf(xv.x, w0.z, a2); a3 = fmaf(xv.x, w0.w, a3);
        a0 = fmaf(xv.y, w1.x, a0); a1 = fmaf(xv.y, w1.y, a1); a2 = fmaf(xv.y, w1.z, a2); a3 = fmaf(xv.y, w1.w, a3);
        a0 = fmaf(xv.z, w2.x, a0); a1 = fmaf(xv.z, w2.y, a1); a2 = fmaf(xv.z, w2.z, a2); a3 = fmaf(xv.z, w2.w, a3);
        a0 = fmaf(xv.w, w3.x, a0); a1 = fmaf(xv.w, w3.y, a1); a2 = fmaf(xv.w, w3.z, a2); a3 = fmaf(xv.w, w3.w, a3);
    }
    float s  = a0 + a1 + a2 + a3;
    float ss = a0*a0 + a1*a1 + a2*a2 + a3*a3;
    s  += __shfl_xor(s, 1);  s  += __shfl_xor(s, 2);
    ss += __shfl_xor(ss, 1); ss += __shfl_xor(ss, 2);
    const float mu   = s * (1.0f/16.0f);
    const float var  = ss * (1.0f/16.0f) - mu*mu;
    const float rstd = rsqrtf(var + 1e-5f);
    const float4 g4 = *(const float4*)&kn_g[c0];
    const float4 b4 = *(const float4*)&kn_b[c0];
    float y0 = (a0 - mu) * rstd * g4.x + b4.x;
    float y1 = (a1 - mu) * rstd * g4.y + b4.y;
    float y2 = (a2 - mu) * rstd * g4.z + b4.z;
    float y3 = (a3 - mu) * rstd * g4.w + b4.w;
    float n2 = y0*y0 + y1*y1 + y2*y2 + y3*y3;
    n2 += __shfl_xor(n2, 1); n2 += __shfl_xor(n2, 2);
    const float inv = 1.0f / fmaxf(sqrtf(n2), 1e-12f);
    float4 o; o.x = y0*inv; o.y = y1*inv; o.z = y2*inv; o.w = y3*inv;
    *(float4*)&ws_k[(b * M_ + m) * RC_ + c0] = o;
}

// ---------------------------------------------------------------------------
// K3: vg = gelu(conv3x1_depthwise(v) + conv_b).  Only center column of the
//     3x3 kernel touches real data (image width is 1 with padding 1).
// ---------------------------------------------------------------------------
__global__ __launch_bounds__(256) void k_conv_kernel(
    const float* __restrict__ ws_v, const float* __restrict__ conv_w,
    const float* __restrict__ conv_b, float* __restrict__ ws_vg)
{
    const int idx = blockIdx.x * 256 + threadIdx.x;  // (b*64+m)*192 + c
    const int c   = idx % C_;
    const int m   = (idx / C_) % M_;
    const float ctr = ws_v[idx];
    const float up  = (m > 0)      ? ws_v[idx - C_] : 0.0f;
    const float dn  = (m < M_ - 1) ? ws_v[idx + C_] : 0.0f;
    const float w0 = conv_w[c*9 + 1];   // kh=0, kw=1
    const float w1 = conv_w[c*9 + 4];   // kh=1, kw=1
    const float w2 = conv_w[c*9 + 7];   // kh=2, kw=1
    float t = conv_b[c];
    t = fmaf(up, w0, t); t = fmaf(ctr, w1, t); t = fmaf(dn, w2, t);
    // exact GELU: 0.5*x*(1+erf(x/sqrt(2)))
    ws_vg[idx] = 0.5f * t * (1.0f + erff(t * 0.70710678118654752f));
}

// ---------------------------------------------------------------------------
// K4: fused main kernel. 64 rows per block; thread = (r = tid>>2, j4 = tid&3).
//   (a) q = l2norm(LN(x@wq+b))            (j4 owns 4 of 16 comps, shfl stats)
//   (b) attn = softmax(q.k / max(T,.5))    (j4 owns 16 of 64 m; k from L1)
//   (c) out = attn @ vg                    (j4 owns 48 of 192 ch; vg from L2)
//   vg (48 KB/batch) and k (4 KB/batch) are shared by all 256 blocks of a
//   batch -> L2/L1-resident; reading them from global instead of LDS cuts
//   LDS 74 KB -> 22.5 KB and lifts occupancy 2 blocks/CU -> 4 blocks/CU.
// ---------------------------------------------------------------------------
__global__ __launch_bounds__(256, 4) void k_main_kernel(
    const float* __restrict__ x, const float* __restrict__ ws_k,
    const float* __restrict__ ws_vg,
    const float* __restrict__ wq_w, const float* __restrict__ wq_b,
    const float* __restrict__ qn_g, const float* __restrict__ qn_b,
    const float* __restrict__ temp,
    float* __restrict__ out, float* __restrict__ attn_out)
{
    __shared__ float attn_s[M_ * 68];      // 17 KB, stride 68: 2-way max
    __shared__ float q_s[M_ * 20];         // 5 KB, stride 20 breaks bank aliasing

    const int tid = threadIdx.x;
    const int b   = blockIdx.x >> 8;
    const int n0  = (blockIdx.x & 255) * M_;

    const int r  = tid >> 2;
    const int j4 = tid & 3;
    const int c0 = j4 * 4;

    // ---- phase (a): q projection + LN + l2norm ----
    const float* xr = x + (size_t)(b * N_ + n0 + r) * C_;
    float a0 = wq_b[c0+0], a1 = wq_b[c0+1], a2 = wq_b[c0+2], a3 = wq_b[c0+3];
    #pragma unroll 4
    for (int d4 = 0; d4 < C_/4; ++d4) {
        const float4 xv = ((const float4*)xr)[d4];
        // all 4 j4 slices of row d live in one 64B line -> broadcast-coalesced
        const float4 w0 = *(const float4*)&wq_w[(d4*4+0)*RC_ + c0];
        const float4 w1 = *(const float4*)&wq_w[(d4*4+1)*RC_ + c0];
        const float4 w2 = *(const float4*)&wq_w[(d4*4+2)*RC_ + c0];
        const float4 w3 = *(const float4*)&wq_w[(d4*4+3)*RC_ + c0];
        a0 = fmaf(xv.x, w0.x, a0); a1 = fmaf(xv.x, w0.y, a1); a2 = fmaf(xv.x, w0.z, a2); a3 = fmaf(xv.x, w0.w, a3);
        a0 = fmaf(xv.y, w1.x, a0); a1 = fmaf(xv.y, w1.y, a1); a2 = fmaf(xv.y, w1.z, a2); a3 = fmaf(xv.y, w1.w, a3);
        a0 = fmaf(xv.z, w2.x, a0); a1 = fmaf(xv.z, w2.y, a1); a2 = fmaf(xv.z, w2.z, a2); a3 = fmaf(xv.z, w2.w, a3);
        a0 = fmaf(xv.w, w3.x, a0); a1 = fmaf(xv.w, w3.y, a1); a2 = fmaf(xv.w, w3.z, a2); a3 = fmaf(xv.w, w3.w, a3);
    }
    {
        float s  = a0 + a1 + a2 + a3;
        float ss = a0*a0 + a1*a1 + a2*a2 + a3*a3;
        s  += __shfl_xor(s, 1);  s  += __shfl_xor(s, 2);
        ss += __shfl_xor(ss, 1); ss += __shfl_xor(ss, 2);
        const float mu   = s * (1.0f/16.0f);
        const float var  = ss * (1.0f/16.0f) - mu*mu;
        const float rstd = rsqrtf(var + 1e-5f);
        const float4 g4 = *(const float4*)&qn_g[c0];
        const float4 b4 = *(const float4*)&qn_b[c0];
        const float y0 = (a0 - mu) * rstd * g4.x + b4.x;
        const float y1 = (a1 - mu) * rstd * g4.y + b4.y;
        const float y2 = (a2 - mu) * rstd * g4.z + b4.z;
        const float y3 = (a3 - mu) * rstd * g4.w + b4.w;
        float n2 = y0*y0 + y1*y1 + y2*y2 + y3*y3;
        n2 += __shfl_xor(n2, 1); n2 += __shfl_xor(n2, 2);
        const float inv = 1.0f / fmaxf(sqrtf(n2), 1e-12f);
        float4 o; o.x = y0*inv; o.y = y1*inv; o.z = y2*inv; o.w = y3*inv;
        *(float4*)&q_s[r*20 + c0] = o;
    }

    __syncthreads();   // q_s visible

    // ---- phase (b): scores + softmax (thread owns m = j4*16 .. +15) ----
    {
        const float tinv = 1.0f / fmaxf(temp[0], 0.5f);
        const float4 q0 = *(const float4*)&q_s[r*20 + 0];
        const float4 q1 = *(const float4*)&q_s[r*20 + 4];
        const float4 q2 = *(const float4*)&q_s[r*20 + 8];
        const float4 q3 = *(const float4*)&q_s[r*20 + 12];
        const float* kb = ws_k + b * (M_ * RC_);
        float sc[16];
        #pragma unroll
        for (int mm = 0; mm < 16; ++mm) {
            const int m = j4*16 + mm;
            // k row from global: 4 KB/batch, L1-resident, broadcast across r-groups
            const float4 k0 = *(const float4*)&kb[m*RC_ + 0];
            const float4 k1 = *(const float4*)&kb[m*RC_ + 4];
            const float4 k2 = *(const float4*)&kb[m*RC_ + 8];
            const float4 k3 = *(const float4*)&kb[m*RC_ + 12];
            float d = q0.x*k0.x;
            d = fmaf(q0.y, k0.y, d); d = fmaf(q0.z, k0.z, d); d = fmaf(q0.w, k0.w, d);
            d = fmaf(q1.x, k1.x, d); d = fmaf(q1.y, k1.y, d); d = fmaf(q1.z, k1.z, d); d = fmaf(q1.w, k1.w, d);
            d = fmaf(q2.x, k2.x, d); d = fmaf(q2.y, k2.y, d); d = fmaf(q2.z, k2.z, d); d = fmaf(q2.w, k2.w, d);
            d = fmaf(q3.x, k3.x, d); d = fmaf(q3.y, k3.y, d); d = fmaf(q3.z, k3.z, d); d = fmaf(q3.w, k3.w, d);
            sc[mm] = d * tinv;
        }
        float mx = sc[0];
        #pragma unroll
        for (int mm = 1; mm < 16; ++mm) mx = fmaxf(mx, sc[mm]);
        mx = fmaxf(mx, __shfl_xor(mx, 1)); mx = fmaxf(mx, __shfl_xor(mx, 2));
        float es = 0.0f;
        #pragma unroll
        for (int mm = 0; mm < 16; ++mm) { sc[mm] = expf(sc[mm] - mx); es += sc[mm]; }
        es += __shfl_xor(es, 1); es += __shfl_xor(es, 2);
        const float einv = 1.0f / es;
        float* aw = attn_out + (size_t)(b * N_ + n0 + r) * M_ + j4*16;
        #pragma unroll
        for (int mq = 0; mq < 4; ++mq) {
            float4 av;
            av.x = sc[mq*4+0]*einv; av.y = sc[mq*4+1]*einv;
            av.z = sc[mq*4+2]*einv; av.w = sc[mq*4+3]*einv;
            *(float4*)&attn_s[r*68 + j4*16 + mq*4] = av;
            nt_store4(aw + mq*4, av.x, av.y, av.z, av.w);  // streaming write
        }
    }

    __syncthreads();   // attn_s visible

    // ---- phase (c): out = attn @ vg  (thread: 48 interleaved channels) ----
    // vg read from global: 48 KB/batch shared by 256 blocks -> L2-resident.
    // Per (m,cc) the 4 j4-lanes cover exactly one 64B line (broadcast over r).
    {
        const float* vgb = ws_vg + b * (M_ * C_);
        float4 acc[12];
        #pragma unroll
        for (int cc = 0; cc < 12; ++cc) { acc[cc].x = 0.f; acc[cc].y = 0.f; acc[cc].z = 0.f; acc[cc].w = 0.f; }
        #pragma unroll 4
        for (int m = 0; m < M_; ++m) {
            const float a = attn_s[r*68 + m];
            const float* vr = vgb + m * C_ + c0;
            #pragma unroll
            for (int cc = 0; cc < 12; ++cc) {
                const float4 v = *(const float4*)&vr[cc*16];
                acc[cc].x = fmaf(a, v.x, acc[cc].x);
                acc[cc].y = fmaf(a, v.y, acc[cc].y);
                acc[cc].z = fmaf(a, v.z, acc[cc].z);
                acc[cc].w = fmaf(a, v.w, acc[cc].w);
            }
        }
        float* orow = out + (size_t)(b * N_ + n0 + r) * C_;
        #pragma unroll
        for (int cc = 0; cc < 12; ++cc)
            nt_store4(&orow[cc*16 + c0], acc[cc].x, acc[cc].y, acc[cc].z, acc[cc].w);
    }
}

// ---------------------------------------------------------------------------
extern "C" void kernel_launch(void* const* d_in, const int* in_sizes, int n_in,
                              void* d_out, int out_size, void* d_ws, size_t ws_size,
                              hipStream_t stream) {
    const float* x      = (const float*)d_in[0];
    const float* dict   = (const float*)d_in[1];
    // d_in[2]=H, d_in[3]=W (unused: M-axis conv only)
    const float* wq_w   = (const float*)d_in[4];
    const float* wq_b   = (const float*)d_in[5];
    const float* wk_w   = (const float*)d_in[6];
    const float* wk_b   = (const float*)d_in[7];
    const float* wv_w   = (const float*)d_in[8];
    const float* wv_b   = (const float*)d_in[9];
    const float* qn_g   = (const float*)d_in[10];
    const float* qn_b   = (const float*)d_in[11];
    const float* kn_g   = (const float*)d_in[12];
    const float* kn_b   = (const float*)d_in[13];
    const float* conv_w = (const float*)d_in[14];
    const float* conv_b = (const float*)d_in[15];
    const float* temp   = (const float*)d_in[16];

    float* out  = (float*)d_out;                          // (B,N,192)
    float* attn = out + (size_t)B_ * N_ * C_;             // (B,N,64)

    float* ws_v  = (float*)d_ws;                          // B*M*C = 98304 f
    float* ws_vg = ws_v  + B_ * M_ * C_;                  // 98304 f
    float* ws_k  = ws_vg + B_ * M_ * C_;                  // 8192 f  (~800KB total)

    k_v_kernel   <<<B_ * M_ * C_ / 256, 256, 0, stream>>>(dict, wv_w, wv_b, ws_v);
    k_k_kernel   <<<B_,                 256, 0, stream>>>(dict, wk_w, wk_b, kn_g, kn_b, ws_k);
    k_conv_kernel<<<B_ * M_ * C_ / 256, 256, 0, stream>>>(ws_v, conv_w, conv_b, ws_vg);
    k_main_kernel<<<B_ * (N_ / M_),     256, 0, stream>>>(x, ws_k, ws_vg, wq_w, wq_b,
                                                          qn_g, qn_b, temp, out, attn);
}

// Round 3
// 343.862 us; speedup vs baseline: 1.7637x; 1.7637x over previous
//
#include <hip/hip_runtime.h>
#include <math.h>

#define B_   8
#define N_   16384
#define M_   64
#define C_   192
#define RC_  16
#define AT_S 68   // attn_t stride in floats: 272 B = 17*16 -> 16B-aligned float4 reads

#define FMA4(acc, s, v) \
    acc.x = fmaf(s, v.x, acc.x); acc.y = fmaf(s, v.y, acc.y); \
    acc.z = fmaf(s, v.z, acc.z); acc.w = fmaf(s, v.w, acc.w)

// ---------------------------------------------------------------------------
// K_prep: fused  v = dict@wv+b  ->  depthwise conv3x1 + GELU  -> ws_vg
//         and    k = l2norm(LN(dict@wk+b))                    -> ws_k
// grid = B*M = 512 blocks (vs 8-block k_k + 384-block k_v/k_conv before).
// threads 0..191: channel c of row (b,m); recompute the 3 needed v-dots
// (rows m-1,m,m+1) directly -> no ws_v round-trip through HBM.
// threads 192..195 (quad, lanes 0..3 of wave 3): k row (b,m).
// ---------------------------------------------------------------------------
__global__ __launch_bounds__(256) void k_prep_kernel(
    const float* __restrict__ dict,
    const float* __restrict__ wv_w, const float* __restrict__ wv_b,
    const float* __restrict__ conv_w, const float* __restrict__ conv_b,
    const float* __restrict__ wk_w, const float* __restrict__ wk_b,
    const float* __restrict__ kn_g, const float* __restrict__ kn_b,
    float* __restrict__ ws_vg, float* __restrict__ ws_k)
{
    const int b   = blockIdx.x >> 6;
    const int m   = blockIdx.x & 63;
    const int tid = threadIdx.x;
    const float* d0 = dict + (b * M_ + m) * C_;

    if (tid < 192) {
        const int c = tid;
        const bool hm = (m > 0), hp = (m < M_ - 1);
        const float* dm = hm ? d0 - C_ : d0;   // clamped; result zeroed below
        const float* dp = hp ? d0 + C_ : d0;
        float am = 0.f, ac = 0.f, ap = 0.f;
        #pragma unroll 4
        for (int d = 0; d < C_; ++d) {
            const float w = wv_w[d * C_ + c];  // coalesced across c
            am = fmaf(dm[d], w, am);           // dm/d0/dp block-uniform -> s_load
            ac = fmaf(d0[d], w, ac);
            ap = fmaf(dp[d], w, ap);
        }
        const float bia = wv_b[c];
        const float up = hm ? (am + bia) : 0.f;   // zero-pad includes bias (ref pads v_img)
        const float ct = ac + bia;
        const float dn = hp ? (ap + bia) : 0.f;
        float t = conv_b[c];
        t = fmaf(up, conv_w[c*9 + 1], t);
        t = fmaf(ct, conv_w[c*9 + 4], t);
        t = fmaf(dn, conv_w[c*9 + 7], t);
        ws_vg[(b * M_ + m) * C_ + c] = 0.5f * t * (1.0f + erff(t * 0.70710678118654752f));
    } else if (tid < 196) {
        const int j4 = tid - 192;              // lanes 0..3 of wave 3 -> one quad
        const int c0 = j4 * 4;
        float a0 = wk_b[c0+0], a1 = wk_b[c0+1], a2 = wk_b[c0+2], a3 = wk_b[c0+3];
        #pragma unroll 4
        for (int d4 = 0; d4 < C_/4; ++d4) {
            const float4 xv = ((const float4*)d0)[d4];
            const float4 w0 = *(const float4*)&wk_w[(d4*4+0)*RC_ + c0];
            const float4 w1 = *(const float4*)&wk_w[(d4*4+1)*RC_ + c0];
            const float4 w2 = *(const float4*)&wk_w[(d4*4+2)*RC_ + c0];
            const float4 w3 = *(const float4*)&wk_w[(d4*4+3)*RC_ + c0];
            a0 = fmaf(xv.x, w0.x, a0); a1 = fmaf(xv.x, w0.y, a1); a2 = fmaf(xv.x, w0.z, a2); a3 = fmaf(xv.x, w0.w, a3);
            a0 = fmaf(xv.y, w1.x, a0); a1 = fmaf(xv.y, w1.y, a1); a2 = fmaf(xv.y, w1.z, a2); a3 = fmaf(xv.y, w1.w, a3);
            a0 = fmaf(xv.z, w2.x, a0); a1 = fmaf(xv.z, w2.y, a1); a2 = fmaf(xv.z, w2.z, a2); a3 = fmaf(xv.z, w2.w, a3);
            a0 = fmaf(xv.w, w3.x, a0); a1 = fmaf(xv.w, w3.y, a1); a2 = fmaf(xv.w, w3.z, a2); a3 = fmaf(xv.w, w3.w, a3);
        }
        float s  = a0 + a1 + a2 + a3;
        float ss = a0*a0 + a1*a1 + a2*a2 + a3*a3;
        s  += __shfl_xor(s, 1);  s  += __shfl_xor(s, 2);
        ss += __shfl_xor(ss, 1); ss += __shfl_xor(ss, 2);
        const float mu   = s * (1.0f/16.0f);
        const float var  = ss * (1.0f/16.0f) - mu*mu;
        const float rstd = rsqrtf(var + 1e-5f);
        const float4 g4 = *(const float4*)&kn_g[c0];
        const float4 b4 = *(const float4*)&kn_b[c0];
        const float y0 = (a0 - mu) * rstd * g4.x + b4.x;
        const float y1 = (a1 - mu) * rstd * g4.y + b4.y;
        const float y2 = (a2 - mu) * rstd * g4.z + b4.z;
        const float y3 = (a3 - mu) * rstd * g4.w + b4.w;
        float n2 = y0*y0 + y1*y1 + y2*y2 + y3*y3;
        n2 += __shfl_xor(n2, 1); n2 += __shfl_xor(n2, 2);
        const float inv = 1.0f / fmaxf(sqrtf(n2), 1e-12f);
        float4 o; o.x = y0*inv; o.y = y1*inv; o.z = y2*inv; o.w = y3*inv;
        *(float4*)&ws_k[(b * M_ + m) * RC_ + c0] = o;
    }
}

// ---------------------------------------------------------------------------
// K_main: 64 rows per block.
//   stage: vg+k global->regs (issued first, T14), LDS-written after phase (a)
//   (a) q = l2norm(LN(x@wq+b))   thread (r=tid>>2, j4): j4 owns 4 of 16 comps
//   (b) softmax scores           thread (r,j4): j4 owns m = 4*mm+j4 (interleaved
//       -> k_s ds_read_b128 is 2-way max); writes attn_t[m][r] (transposed)
//   (c) out = attn @ vg          thread (rq=tid>>4, cq): 4 rows x 12 ch tile
//       -> 64 B/thread/m LDS traffic vs 192 B before (3x LDS-BW cut)
// ---------------------------------------------------------------------------
__global__ __launch_bounds__(256, 2) void k_main_kernel(
    const float* __restrict__ x, const float* __restrict__ ws_k,
    const float* __restrict__ ws_vg,
    const float* __restrict__ wq_w, const float* __restrict__ wq_b,
    const float* __restrict__ qn_g, const float* __restrict__ qn_b,
    const float* __restrict__ temp,
    float* __restrict__ out, float* __restrict__ attn_out)
{
    __shared__ float vg_s[M_ * C_];        // 48 KB
    __shared__ float k_s[M_ * RC_];        // 4 KB
    __shared__ float attn_t[M_ * AT_S];    // 17 KB   [m][row], stride 68

    const int tid   = threadIdx.x;
    const int b     = blockIdx.x >> 8;
    const int n0    = (blockIdx.x & 255) * M_;
    const int lane  = tid & 63;
    const int lbase = lane & ~3;

    // ---- T14 stage-issue: global->regs now; LDS write deferred to after (a) ----
    float4 st[12]; float4 kst;
    {
        const float4* vgb4 = (const float4*)(ws_vg + b * (M_ * C_));
        #pragma unroll
        for (int i = 0; i < 12; ++i) st[i] = vgb4[tid + 256 * i];
        kst = ((const float4*)(ws_k + b * (M_ * RC_)))[tid];
    }

    const int r  = tid >> 2;
    const int j4 = tid & 3;
    const int c0 = j4 * 4;

    // ---- phase (a): q projection + LN + l2norm (hides staging-load latency) ----
    const float* xr = x + (size_t)(b * N_ + n0 + r) * C_;
    float a0 = wq_b[c0+0], a1 = wq_b[c0+1], a2 = wq_b[c0+2], a3 = wq_b[c0+3];
    #pragma unroll 4
    for (int d4 = 0; d4 < C_/4; ++d4) {
        const float4 xv = ((const float4*)xr)[d4];
        const float4 w0 = *(const float4*)&wq_w[(d4*4+0)*RC_ + c0];
        const float4 w1 = *(const float4*)&wq_w[(d4*4+1)*RC_ + c0];
        const float4 w2 = *(const float4*)&wq_w[(d4*4+2)*RC_ + c0];
        const float4 w3 = *(const float4*)&wq_w[(d4*4+3)*RC_ + c0];
        a0 = fmaf(xv.x, w0.x, a0); a1 = fmaf(xv.x, w0.y, a1); a2 = fmaf(xv.x, w0.z, a2); a3 = fmaf(xv.x, w0.w, a3);
        a0 = fmaf(xv.y, w1.x, a0); a1 = fmaf(xv.y, w1.y, a1); a2 = fmaf(xv.y, w1.z, a2); a3 = fmaf(xv.y, w1.w, a3);
        a0 = fmaf(xv.z, w2.x, a0); a1 = fmaf(xv.z, w2.y, a1); a2 = fmaf(xv.z, w2.z, a2); a3 = fmaf(xv.z, w2.w, a3);
        a0 = fmaf(xv.w, w3.x, a0); a1 = fmaf(xv.w, w3.y, a1); a2 = fmaf(xv.w, w3.z, a2); a3 = fmaf(xv.w, w3.w, a3);
    }
    float4 q[4];   // full 16-comp q row, quad all-gather
    {
        float s  = a0 + a1 + a2 + a3;
        float ss = a0*a0 + a1*a1 + a2*a2 + a3*a3;
        s  += __shfl_xor(s, 1);  s  += __shfl_xor(s, 2);
        ss += __shfl_xor(ss, 1); ss += __shfl_xor(ss, 2);
        const float mu   = s * (1.0f/16.0f);
        const float var  = ss * (1.0f/16.0f) - mu*mu;
        const float rstd = rsqrtf(var + 1e-5f);
        const float4 g4 = *(const float4*)&qn_g[c0];
        const float4 b4 = *(const float4*)&qn_b[c0];
        const float y0 = (a0 - mu) * rstd * g4.x + b4.x;
        const float y1 = (a1 - mu) * rstd * g4.y + b4.y;
        const float y2 = (a2 - mu) * rstd * g4.z + b4.z;
        const float y3 = (a3 - mu) * rstd * g4.w + b4.w;
        float n2 = y0*y0 + y1*y1 + y2*y2 + y3*y3;
        n2 += __shfl_xor(n2, 1); n2 += __shfl_xor(n2, 2);
        const float inv = 1.0f / fmaxf(sqrtf(n2), 1e-12f);
        float4 o; o.x = y0*inv; o.y = y1*inv; o.z = y2*inv; o.w = y3*inv;
        #pragma unroll
        for (int j = 0; j < 4; ++j) {
            q[j].x = __shfl(o.x, lbase + j);
            q[j].y = __shfl(o.y, lbase + j);
            q[j].z = __shfl(o.z, lbase + j);
            q[j].w = __shfl(o.w, lbase + j);
        }
    }
    const float tinv = 1.0f / fmaxf(temp[0], 0.5f);

    // ---- stage-write: regs -> LDS (loads long complete), then one barrier ----
    {
        #pragma unroll
        for (int i = 0; i < 12; ++i) ((float4*)vg_s)[tid + 256 * i] = st[i];
        ((float4*)k_s)[tid] = kst;
    }
    __syncthreads();

    // ---- phase (b): scores + softmax; thread owns m = 4*mm + j4 ----
    {
        float sc[16];
        #pragma unroll
        for (int mm = 0; mm < 16; ++mm) {
            const int m = mm*4 + j4;
            const float4 k0 = *(const float4*)&k_s[m*RC_ + 0];
            const float4 k1 = *(const float4*)&k_s[m*RC_ + 4];
            const float4 k2 = *(const float4*)&k_s[m*RC_ + 8];
            const float4 k3 = *(const float4*)&k_s[m*RC_ + 12];
            float d = q[0].x*k0.x;
            d = fmaf(q[0].y, k0.y, d); d = fmaf(q[0].z, k0.z, d); d = fmaf(q[0].w, k0.w, d);
            d = fmaf(q[1].x, k1.x, d); d = fmaf(q[1].y, k1.y, d); d = fmaf(q[1].z, k1.z, d); d = fmaf(q[1].w, k1.w, d);
            d = fmaf(q[2].x, k2.x, d); d = fmaf(q[2].y, k2.y, d); d = fmaf(q[2].z, k2.z, d); d = fmaf(q[2].w, k2.w, d);
            d = fmaf(q[3].x, k3.x, d); d = fmaf(q[3].y, k3.y, d); d = fmaf(q[3].z, k3.z, d); d = fmaf(q[3].w, k3.w, d);
            sc[mm] = d * tinv;
        }
        float mx = sc[0];
        #pragma unroll
        for (int mm = 1; mm < 16; ++mm) mx = fmaxf(mx, sc[mm]);
        mx = fmaxf(mx, __shfl_xor(mx, 1)); mx = fmaxf(mx, __shfl_xor(mx, 2));
        float es = 0.0f;
        #pragma unroll
        for (int mm = 0; mm < 16; ++mm) { sc[mm] = expf(sc[mm] - mx); es += sc[mm]; }
        es += __shfl_xor(es, 1); es += __shfl_xor(es, 2);
        const float einv = 1.0f / es;
        float* aw = attn_out + (size_t)(b * N_ + n0 + r) * M_;
        #pragma unroll
        for (int mm = 0; mm < 16; ++mm) {
            const float p = sc[mm] * einv;
            attn_t[(mm*4 + j4)*AT_S + r] = p;   // transposed for phase (c)
            aw[mm*4 + j4] = p;                  // global attn output
        }
    }
    __syncthreads();

    // ---- phase (c): out = attn @ vg; thread (rq,cq) = 4 rows x 12 channels ----
    {
        const int rq = tid >> 4;       // rows 4rq .. 4rq+3
        const int cq = tid & 15;       // channels cq*12 .. cq*12+11
        float4 ac0[3], ac1[3], ac2[3], ac3[3];
        #pragma unroll
        for (int t = 0; t < 3; ++t) {
            ac0[t] = make_float4(0.f,0.f,0.f,0.f);
            ac1[t] = make_float4(0.f,0.f,0.f,0.f);
            ac2[t] = make_float4(0.f,0.f,0.f,0.f);
            ac3[t] = make_float4(0.f,0.f,0.f,0.f);
        }
        #pragma unroll 4
        for (int m = 0; m < M_; ++m) {
            const float4 av = *(const float4*)&attn_t[m*AT_S + rq*4];  // 4 rows, col m
            const float4* vr = (const float4*)(vg_s + m*C_ + cq*12);
            #pragma unroll
            for (int t = 0; t < 3; ++t) {
                const float4 v = vr[t];
                FMA4(ac0[t], av.x, v);
                FMA4(ac1[t], av.y, v);
                FMA4(ac2[t], av.z, v);
                FMA4(ac3[t], av.w, v);
            }
        }
        float* o0 = out + (size_t)(b * N_ + n0 + rq*4) * C_ + cq*12;
        #pragma unroll
        for (int t = 0; t < 3; ++t) {
            *(float4*)&o0[t*4]          = ac0[t];
            *(float4*)&o0[C_   + t*4]   = ac1[t];
            *(float4*)&o0[2*C_ + t*4]   = ac2[t];
            *(float4*)&o0[3*C_ + t*4]   = ac3[t];
        }
    }
}

// ---------------------------------------------------------------------------
extern "C" void kernel_launch(void* const* d_in, const int* in_sizes, int n_in,
                              void* d_out, int out_size, void* d_ws, size_t ws_size,
                              hipStream_t stream) {
    const float* x      = (const float*)d_in[0];
    const float* dict   = (const float*)d_in[1];
    const float* wq_w   = (const float*)d_in[4];
    const float* wq_b   = (const float*)d_in[5];
    const float* wk_w   = (const float*)d_in[6];
    const float* wk_b   = (const float*)d_in[7];
    const float* wv_w   = (const float*)d_in[8];
    const float* wv_b   = (const float*)d_in[9];
    const float* qn_g   = (const float*)d_in[10];
    const float* qn_b   = (const float*)d_in[11];
    const float* kn_g   = (const float*)d_in[12];
    const float* kn_b   = (const float*)d_in[13];
    const float* conv_w = (const float*)d_in[14];
    const float* conv_b = (const float*)d_in[15];
    const float* temp   = (const float*)d_in[16];

    float* out  = (float*)d_out;                          // (B,N,192)
    float* attn = out + (size_t)B_ * N_ * C_;             // (B,N,64)

    float* ws_vg = (float*)d_ws;                          // B*M*C = 98304 f
    float* ws_k  = ws_vg + B_ * M_ * C_;                  // 8192 f

    k_prep_kernel<<<B_ * M_,        256, 0, stream>>>(dict, wv_w, wv_b, conv_w, conv_b,
                                                      wk_w, wk_b, kn_g, kn_b, ws_vg, ws_k);
    k_main_kernel<<<B_ * (N_ / M_), 256, 0, stream>>>(x, ws_k, ws_vg, wq_w, wq_b,
                                                      qn_g, qn_b, temp, out, attn);
}